// Round 3
// baseline (418.418 us; speedup 1.0000x reference)
//
#include <hip/hip_runtime.h>

// Izhikevich neuron scan: B=16, T=1000, D=4096, fp32.
// One thread per neuron (65,536 threads = 1024 waves = 1 wave/SIMD chip-wide:
// max parallelism; t-recurrence is strictly sequential). Memory-bound:
// 524 MB compulsory traffic -> ~83 us kernel floor @ 6.3 TB/s.
//
// R2 post-mortem: ping-pong prefetch lead = 1 batch of compute (~680 cyc)
// < effective HBM latency under load (~900-1300 cyc) -> stall at every batch
// boundary, 66% BW efficiency. With 1 wave/SIMD there is no TLP; the lead
// time itself must exceed latency.
// R3: prefetch distance TWO batches via 4-slot register ring, U=25 (NB=40,
// divisible by 4). Lead ~= 50 steps ~= 1700 cyc >> latency; up to 50 KB/CU
// in flight >> 9.2 KB Little's-law requirement. ~130 VGPRs is free at
// 1 wave/SIMD (__launch_bounds__(256,1)).
//
// NUMERICS: chaotic near v=30 -> must match XLA bit-exactly: strict
// left-to-right fp32, no FMA contraction. Verified absmax=0 in R1/R2.

constexpr int T_STEPS = 1000;
constexpr int D_DIM   = 4096;
constexpr int U       = 25;               // batch depth
constexpr int NB      = T_STEPS / U;      // 40 batches, NB % 4 == 0

__global__ __launch_bounds__(256, 1)
void izhikevich_kernel(const float* __restrict__ I, float* __restrict__ out, int BD) {
    #pragma clang fp contract(off)
    int n = blockIdx.x * 256 + threadIdx.x;
    if (n >= BD) return;
    int b = n / D_DIM;
    int d = n % D_DIM;
    const size_t base = (size_t)b * T_STEPS * D_DIM + d;
    const float* ip = I + base;
    float*       op = out + base;

    float v = -65.0f;
    float u = 0.2f * -65.0f;   // B_P * V_INIT

    // One timestep; strict evaluation order (matches JAX/XLA bit-exactly).
    auto step = [&](float i_t, float* o) {
        float dv = 0.04f * v * v + 5.0f * v + 140.0f - u + i_t;
        v = v + 0.2f * dv;
        float du = 0.02f * (0.2f * v - u);
        u = u + 0.2f * du;
        bool s = (v >= 30.0f);
        __builtin_nontemporal_store(s ? 1.0f : 0.0f, o);
        if (s) { v = -65.0f; u = u + 6.0f; }
    };

    float buf[4][U];   // 4-slot ring, prefetch distance 2 batches

    // Preload batches 0 and 1.
    #pragma unroll
    for (int j = 0; j < U; ++j)
        buf[0][j] = __builtin_nontemporal_load(ip + (size_t)j * D_DIM);
    #pragma unroll
    for (int j = 0; j < U; ++j)
        buf[1][j] = __builtin_nontemporal_load(ip + (size_t)(U + j) * D_DIM);

    for (int ob = 0; ob < NB; ob += 4) {
        #pragma unroll
        for (int p = 0; p < 4; ++p) {
            int bb = ob + p;
            // Prefetch batch bb+2 into ring slot (p+2)&3 (uniform branch;
            // false only for the last two batches).
            if (bb + 2 < NB) {
                const float* pp = ip + (size_t)(bb + 2) * U * D_DIM;
                #pragma unroll
                for (int j = 0; j < U; ++j)
                    buf[(p + 2) & 3][j] =
                        __builtin_nontemporal_load(pp + (size_t)j * D_DIM);
            }
            // Consume batch bb from ring slot p.
            float* oo = op + (size_t)bb * U * D_DIM;
            #pragma unroll
            for (int j = 0; j < U; ++j)
                step(buf[p][j], oo + (size_t)j * D_DIM);
        }
    }
}

extern "C" void kernel_launch(void* const* d_in, const int* in_sizes, int n_in,
                              void* d_out, int out_size, void* d_ws, size_t ws_size,
                              hipStream_t stream) {
    const float* I  = (const float*)d_in[0];
    float*      out = (float*)d_out;
    int total = in_sizes[0];            // B*T*D
    int BD    = total / T_STEPS;        // 65,536 neurons
    int block = 256;
    int grid  = (BD + block - 1) / block;
    izhikevich_kernel<<<grid, block, 0, stream>>>(I, out, BD);
}